// Round 1
// 1743.796 us; speedup vs baseline: 1.1825x; 1.1825x over previous
//
#include <hip/hip_runtime.h>
#include <hip/hip_bf16.h>

// Problem constants
#define QN    2048
#define NN    100000
#define DD    1024
#define CC    1000
#define KK    50
#define BROWS 100096   // NN padded to multiple of 128
#define NBLK  782      // BROWS / 128

typedef _Float16 f16x8 __attribute__((ext_vector_type(8)));
typedef float f32x4  __attribute__((ext_vector_type(4)));

__device__ __forceinline__ short f2h(float x) {
    _Float16 h = (_Float16)x;                    // RN
    return (short)__builtin_bit_cast(unsigned short, h);
}
__device__ __forceinline__ float h2f(short s) {
    _Float16 h = __builtin_bit_cast(_Float16, (unsigned short)s);
    return (float)h;
}

// ---------------- convert: fp32 -> fp16 hi (+ optional fp16 lo residual) ----------------
// 2-term scheme: scores = (Ahi+Alo)·Bhi. A needs hi+lo (A quantization ~2^-22);
// B needs hi only (error a·(b-bh) ~ 1.5e-5 typical << top-50 boundary gap ~2.3e-3).
__global__ __launch_bounds__(256) void knn_convert(
    const float* __restrict__ src, short* __restrict__ hi, short* __restrict__ lo,
    int rows_valid, int write_lo)
{
    const int n  = blockIdx.x;
    const int k4 = threadIdx.x << 2;
    float4 v = make_float4(0.f, 0.f, 0.f, 0.f);
    if (n < rows_valid)
        v = *reinterpret_cast<const float4*>(&src[(size_t)n * DD + k4]);

    short h0 = f2h(v.x), h1 = f2h(v.y), h2 = f2h(v.z), h3 = f2h(v.w);
    *reinterpret_cast<short4*>(&hi[(size_t)n * DD + k4]) =
        make_short4(h0, h1, h2, h3);
    if (write_lo) {
        short4 lv = make_short4(f2h(v.x - h2f(h0)), f2h(v.y - h2f(h1)),
                                f2h(v.z - h2f(h2)), f2h(v.w - h2f(h3)));
        *reinterpret_cast<short4*>(&lo[(size_t)n * DD + k4]) = lv;
    }
}

// ---------------- MFMA GEMM + fused per-(row,128col-block) argmax ----------------
// 128x128 tile, BK=32, 4 waves (64x64 each via 4x4 of 16x16x32 f16).
// 2 MFMA per fragment pair: acc += ahi*bh; acc += alo*bh.
// LDS chunk-XOR swizzle: slot chunk c_slot holds data chunk c_slot ^ ((row>>1)&3)
// so fragment ds_read_b128 spreads over all 32 banks (2-way, free) instead of
// 8-way on banks {0-3,16-19}.
#define GL(gptr, ldsptr) __builtin_amdgcn_global_load_lds(                    \
    (const __attribute__((address_space(1))) void*)(gptr),                    \
    (__attribute__((address_space(3))) void*)(ldsptr), 16, 0, 0)

__global__ __launch_bounds__(256) void knn_gemm(
    const short* __restrict__ Ahi, const short* __restrict__ Alo,
    const short* __restrict__ Bhi,
    float* __restrict__ out, float* __restrict__ bm_s, int* __restrict__ bm_i)
{
    __shared__ short As_hi[128][32];
    __shared__ short As_lo[128][32];
    __shared__ short Bs_hi[128][32];
    __shared__ float red_s[2][128];
    __shared__ int   red_i[2][128];

    const int tid  = threadIdx.x;
    const int lane = tid & 63;
    const int w    = tid >> 6;
    const int wm   = (w >> 1) * 64;      // wave's M offset in tile
    const int wn   = (w & 1) * 64;       // wave's N offset in tile
    const int q0   = blockIdx.x * 128;   // q on x: adjacent blocks share B tile
    const int c0   = blockIdx.y * 128;

    const int srow = w * 32 + (lane >> 2);                    // staging row (GL#1), +16 for GL#2
    const int kb   = (((lane & 3) ^ ((lane >> 3) & 3)) * 16); // swizzled chunk byte offset
    const int fr   = lane & 15;              // fragment row (m or n)
    const int fq   = lane >> 4;              // fragment quad (k-chunk)

    f32x4 acc[4][4];
    #pragma unroll
    for (int i = 0; i < 4; ++i)
        #pragma unroll
        for (int j = 0; j < 4; ++j)
            acc[i][j] = (f32x4){0.f, 0.f, 0.f, 0.f};

    const size_t arow = (size_t)(q0 + srow);
    const size_t brow = (size_t)(c0 + srow);
    char* lds_ah = (char*)As_hi + (w * 32) * 64;   // wave-uniform LDS bases
    char* lds_al = (char*)As_lo + (w * 32) * 64;
    char* lds_bh = (char*)Bs_hi + (w * 32) * 64;

    for (int k0 = 0; k0 < DD; k0 += 32) {
        const size_t ab = (arow * DD + k0) * 2 + kb;     // byte offsets
        const size_t bb = (brow * DD + k0) * 2 + kb;
        const size_t rstep = (size_t)16 * DD * 2;        // +16 rows

        GL((const char*)Ahi + ab,         lds_ah);
        GL((const char*)Ahi + ab + rstep, lds_ah + 16 * 64);
        GL((const char*)Alo + ab,         lds_al);
        GL((const char*)Alo + ab + rstep, lds_al + 16 * 64);
        GL((const char*)Bhi + bb,         lds_bh);
        GL((const char*)Bhi + bb + rstep, lds_bh + 16 * 64);
        __syncthreads();   // drains vmcnt(0) before barrier

        f16x8 ah[4], al[4], bh[4];
        #pragma unroll
        for (int i = 0; i < 4; ++i) {
            const int ra = wm + i * 16 + fr;
            const int rb = wn + i * 16 + fr;
            const int ca = (fq ^ ((ra >> 1) & 3)) * 8;   // swizzled read chunk
            const int cb = (fq ^ ((rb >> 1) & 3)) * 8;
            ah[i] = *reinterpret_cast<const f16x8*>(&As_hi[ra][ca]);
            al[i] = *reinterpret_cast<const f16x8*>(&As_lo[ra][ca]);
            bh[i] = *reinterpret_cast<const f16x8*>(&Bs_hi[rb][cb]);
        }

        #pragma unroll
        for (int i = 0; i < 4; ++i)
            #pragma unroll
            for (int j = 0; j < 4; ++j) {
                acc[i][j] = __builtin_amdgcn_mfma_f32_16x16x32_f16(ah[i], bh[j], acc[i][j], 0, 0, 0);
                acc[i][j] = __builtin_amdgcn_mfma_f32_16x16x32_f16(al[i], bh[j], acc[i][j], 0, 0, 0);
            }
        __syncthreads();
    }

    // epilogue: D layout col=lane&15, row=(lane>>4)*4+reg  [m89-verified]
    // write scores (padded cols -> -1e30) + fused per-row max over this block's cols
    #pragma unroll
    for (int i = 0; i < 4; ++i) {
        const int qrow = q0 + wm + i * 16 + fq * 4;
        float rv[4]; int rc[4];
        #pragma unroll
        for (int r = 0; r < 4; ++r) { rv[r] = -3e30f; rc[r] = 0; }
        #pragma unroll
        for (int j = 0; j < 4; ++j) {
            const int col = c0 + wn + j * 16 + fr;
            const bool ok = (col < NN);
            float* dst = &out[(size_t)qrow * BROWS + col];
            #pragma unroll
            for (int r = 0; r < 4; ++r) {
                float v = ok ? acc[i][j][r] : -1e30f;
                dst[r * (size_t)BROWS] = v;
                if (v > rv[r]) { rv[r] = v; rc[r] = col; }   // ascending j: ties keep smaller col
            }
        }
        #pragma unroll
        for (int r = 0; r < 4; ++r) {
            float v = rv[r]; int c = rc[r];
            #pragma unroll
            for (int m = 1; m <= 8; m <<= 1) {               // reduce across fr (16-lane group)
                float ov = __shfl_xor(v, m);
                int   oc = __shfl_xor(c, m);
                if (ov > v || (ov == v && oc < c)) { v = ov; c = oc; }
            }
            if (fr == 0) {
                red_s[w & 1][wm + i * 16 + fq * 4 + r] = v;
                red_i[w & 1][wm + i * 16 + fq * 4 + r] = c;
            }
        }
    }
    __syncthreads();
    if (tid < 128) {
        float v0 = red_s[0][tid], v1 = red_s[1][tid];
        int   i0 = red_i[0][tid], i1 = red_i[1][tid];
        bool take1 = (v1 > v0) || (v1 == v0 && i1 < i0);
        bm_s[(size_t)(q0 + tid) * NBLK + blockIdx.y] = take1 ? v1 : v0;
        bm_i[(size_t)(q0 + tid) * NBLK + blockIdx.y] = take1 ? i1 : i0;
    }
}

// ---------------- merge: per-query top-50 from 782 block maxima ----------------
// one wave per query; 50 rounds of (LDS argmax over 782 + 128-elem slice rescan)
__global__ __launch_bounds__(64) void knn_merge(
    float* __restrict__ sc,
    const float* __restrict__ bm_s, const int* __restrict__ bm_i,
    float* __restrict__ top_s, int* __restrict__ top_i)
{
    const int q = blockIdx.x;
    const int t = threadIdx.x;

    __shared__ float pool_s[NBLK];
    __shared__ int   pool_i[NBLK];
    __shared__ float win_s[KK];
    __shared__ int   win_i[KK];

    float* row = sc + (size_t)q * BROWS;

    for (int e = t; e < NBLK; e += 64) {
        pool_s[e] = bm_s[(size_t)q * NBLK + e];
        pool_i[e] = bm_i[(size_t)q * NBLK + e];
    }
    __syncthreads();

    for (int r = 0; r < KK; ++r) {
        // argmax over pool; pool order == col order, so tie -> smaller e == smaller col
        float bs = -3e30f; int be = 0;
        for (int e = t; e < NBLK; e += 64) {
            float v = pool_s[e];
            if (v > bs) { bs = v; be = e; }
        }
        #pragma unroll
        for (int m = 32; m; m >>= 1) {
            float ov = __shfl_xor(bs, m);
            int   oe = __shfl_xor(be, m);
            if (ov > bs || (ov == bs && oe < be)) { bs = ov; be = oe; }
        }
        if (t == 0) {
            win_s[r] = bs;
            win_i[r] = pool_i[be];
            row[pool_i[be]] = -1e30f;            // mark taken
        }
        __syncthreads();                          // mark visible before rescan

        {   // rescan winning 128-col slice
            const int base = be * 128;
            float v0 = row[base + t], v1 = row[base + 64 + t];
            int   i0 = base + t,      i1 = base + 64 + t;
            if (v1 > v0) { v0 = v1; i0 = i1; }
            #pragma unroll
            for (int m = 32; m; m >>= 1) {
                float ov = __shfl_xor(v0, m);
                int   oi = __shfl_xor(i0, m);
                if (ov > v0 || (ov == v0 && oi < i0)) { v0 = ov; i0 = oi; }
            }
            if (t == 0) { pool_s[be] = v0; pool_i[be] = i0; }
        }
        __syncthreads();
    }

    if (t < KK) { top_s[q * 64 + t] = win_s[t]; top_i[q * 64 + t] = win_i[t]; }
    else        { top_s[q * 64 + t] = -1e30f;   top_i[q * 64 + t] = 0; }
}

// ---------------- vote: class histogram, normalize, write preds + targets ----------------
__global__ __launch_bounds__(256) void knn_vote(
    const float* __restrict__ top_s, const int* __restrict__ top_i,
    const int* __restrict__ labels, const int* __restrict__ targets,
    float* __restrict__ out)
{
    const int q = blockIdx.x;
    const int t = threadIdx.x;
    __shared__ float hist[CC];
    __shared__ float ssum;

    for (int c = t; c < CC; c += 256) hist[c] = 0.f;
    if (t == 0) ssum = 0.f;
    __syncthreads();

    if (t < KK) {
        float s = top_s[q * 64 + t];
        int   idx = top_i[q * 64 + t];
        if (s > -1e29f) {
            int lab = labels[idx];
            atomicAdd(&hist[lab], s);
            atomicAdd(&ssum, s);
        }
    }
    __syncthreads();

    float denom = ssum;
    if (denom == 0.f) denom = 1.f;
    float inv = 1.f / denom;
    for (int c = t; c < CC; c += 256)
        out[(size_t)q * CC + c] = hist[c] * inv;
    if (t == 0)
        out[(size_t)QN * CC + q] = (float)targets[q];
}

// ---------------- host launch ----------------
extern "C" void kernel_launch(void* const* d_in, const int* in_sizes, int n_in,
                              void* d_out, int out_size, void* d_ws, size_t ws_size,
                              hipStream_t stream) {
    const float* samples = (const float*)d_in[0];   // [QN][DD]
    const int*   targets = (const int*)d_in[1];     // [QN]
    const float* train   = (const float*)d_in[2];   // [NN][DD]
    const int*   labels  = (const int*)d_in[3];     // [NN]
    float* out = (float*)d_out;

    char* ws = (char*)d_ws;
    short* Ahi = (short*)ws;                                     // 4MB
    short* Alo = Ahi + (size_t)QN * DD;                          // 4MB
    short* Bhi = (short*)(ws + (16 << 20));                      // 195.5MB
    // (former Blo slot left unused; offsets kept identical to previous layout)
    size_t bm_off = (size_t)(16 << 20) + 2 * (size_t)BROWS * DD * 2;
    float* bm_s = (float*)(ws + bm_off);                         // 2048*782*4 ≈ 6.1MB
    int*   bm_i = (int*)(ws + bm_off + (8 << 20));               // ≈ 6.1MB
    float* top_s = (float*)(ws + bm_off + (16 << 20));           // 512KB
    int*   top_i = (int*)(ws + bm_off + (17 << 20));             // 512KB
    float* scores = (float*)(ws + bm_off + (18 << 20));          // 2048*100096*4 ≈ 820MB

    knn_convert<<<QN,    256, 0, stream>>>(samples, Ahi, Alo, QN, 1);
    knn_convert<<<BROWS, 256, 0, stream>>>(train,   Bhi, nullptr, NN, 0);

    dim3 grid(QN / 128, NBLK);    // q on x (fastest) -> 16 consecutive blocks share B tile
    knn_gemm<<<grid, 256, 0, stream>>>(Ahi, Alo, Bhi, scores, bm_s, bm_i);

    knn_merge<<<QN, 64, 0, stream>>>(scores, bm_s, bm_i, top_s, top_i);
    knn_vote<<<QN, 256, 0, stream>>>(top_s, top_i, labels, targets, out);
}